// Round 1
// baseline (2326.754 us; speedup 1.0000x reference)
//
#include <hip/hip_runtime.h>
#include <hip/hip_bf16.h>
#include <stdint.h>

typedef __bf16 bf16x8 __attribute__((ext_vector_type(8)));
typedef float f32x4 __attribute__((ext_vector_type(4)));
using bf16 = __hip_bfloat16;

namespace {
constexpr int B_  = 4;
constexpr int S1_ = 768;
constexpr int S2_ = 64;
constexpr int S_  = 832;
constexpr int D0_ = 2048;
constexpr int F0_ = 16384;
constexpr int D1_ = 1024;
constexpr int F1_ = 4096;
constexpr int H_  = 8;
constexpr int HD_ = 256;
constexpr int HHD_ = 2048;  // H*HD
}

// ---------------------------------------------------------------------------
// Weight transpose+convert: fp32 [K][N] row-major -> bf16 [N][K] row-major
// ---------------------------------------------------------------------------
__global__ __launch_bounds__(256) void transpose_bf16_kernel(
    const float* __restrict__ src, bf16* __restrict__ dst, int K, int N) {
  __shared__ float tile[32][33];
  const int k0 = blockIdx.y * 32, n0 = blockIdx.x * 32;
  const int tc = threadIdx.x & 31, tr = threadIdx.x >> 5;  // 8 rows x 32 cols
#pragma unroll
  for (int i = 0; i < 4; i++)
    tile[tr + i * 8][tc] = src[(size_t)(k0 + tr + i * 8) * N + n0 + tc];
  __syncthreads();
#pragma unroll
  for (int i = 0; i < 4; i++)
    dst[(size_t)(n0 + tr + i * 8) * K + k0 + tc] =
        __float2bfloat16(tile[tc][tr + i * 8]);
}

// ---------------------------------------------------------------------------
// Sequential per-batch cumsum for pos (pad) and cs (att)
// ---------------------------------------------------------------------------
__global__ void scan_kernel(const int* __restrict__ pad, const int* __restrict__ att,
                            int* __restrict__ pos, int* __restrict__ cs) {
  int b = threadIdx.x;
  if (b < B_) {
    int c1 = 0, c2 = 0;
    for (int s = 0; s < S_; s++) {
      c1 += pad[b * S_ + s]; pos[b * S_ + s] = c1 - 1;
      c2 += att[b * S_ + s]; cs[b * S_ + s] = c2;
    }
  }
}

// ---------------------------------------------------------------------------
// AdaLN modulation: out[b][j] = bias[j] + sum_d cond[b][d]*w[d][j]   (fp32)
// ---------------------------------------------------------------------------
__global__ __launch_bounds__(256) void ada_kernel(
    const float* __restrict__ cond, const float* __restrict__ w,
    const float* __restrict__ bias, float* __restrict__ out) {
  const int b = blockIdx.y;
  const int j = blockIdx.x * 256 + threadIdx.x;
  float acc = bias[j];
  const float* c = cond + (size_t)b * D1_;
  for (int d = 0; d < D1_; d++) acc += c[d] * w[(size_t)d * (2 * D1_) + j];
  out[(size_t)b * (2 * D1_) + j] = acc;
}

// ---------------------------------------------------------------------------
// RMSNorm -> bf16.  PERB: weight row selected by (row / rows_per_b) (AdaLN scale)
// ---------------------------------------------------------------------------
template <bool PERB>
__global__ __launch_bounds__(256) void rms_kernel(
    const float* __restrict__ x, int D, const float* __restrict__ w,
    int wstride, int rows_per_b, bf16* __restrict__ out) {
  const int row = blockIdx.x;
  const float* xr = x + (size_t)row * D;
  const int tid = threadIdx.x;
  float ss = 0.f;
  for (int i = tid; i < D; i += 256) { float v = xr[i]; ss += v * v; }
  for (int m = 1; m < 64; m <<= 1) ss += __shfl_xor(ss, m);
  __shared__ float red[4];
  if ((tid & 63) == 0) red[tid >> 6] = ss;
  __syncthreads();
  float tot = red[0] + red[1] + red[2] + red[3];
  float r = rsqrtf(tot / (float)D + 1e-6f);
  const float* wp = PERB ? (w + (size_t)(row / rows_per_b) * wstride) : w;
  for (int i = tid; i < D; i += 256)
    out[(size_t)row * D + i] = __float2bfloat16(xr[i] * r * (1.f + wp[i]));
}

// ---------------------------------------------------------------------------
// RoPE + pack into joint-sequence bf16 buffers.  V stored transposed [B][HD][S].
// ---------------------------------------------------------------------------
__global__ __launch_bounds__(256) void rope_pack_kernel(
    const float* __restrict__ q0f, const float* __restrict__ q1f,
    const float* __restrict__ k0f, const float* __restrict__ k1f,
    const bf16* __restrict__ v0b, const bf16* __restrict__ v1b,
    const int* __restrict__ pos,
    bf16* __restrict__ qbf, bf16* __restrict__ kbf, bf16* __restrict__ vT) {
  const int bs = blockIdx.x;
  const int b = bs / S_, s = bs % S_;
  const float p = (float)pos[b * S_ + s];
  const bool st0 = (s < S1_);
  const float* qs = st0 ? q0f + (size_t)(b * S1_ + s) * HHD_
                        : q1f + (size_t)(b * S2_ + s - S1_) * HHD_;
  const float* ks = st0 ? k0f + (size_t)(b * S1_ + s) * HD_
                        : k1f + (size_t)(b * S2_ + s - S1_) * HD_;
  const bf16* vs = st0 ? v0b + (size_t)(b * S1_ + s) * HD_
                       : v1b + (size_t)(b * S2_ + s - S1_) * HD_;
  const float LN = 0.07195578415606394f;  // ln(10000)/128
  for (int idx = threadIdx.x; idx < HHD_ + 2 * HD_; idx += 256) {
    if (idx < HHD_) {
      int d = idx & 255, i = d & 127;
      float fr = p * expf(-LN * (float)i);
      float c = cosf(fr), sn = sinf(fr);
      float v = (d < 128) ? qs[idx] * c - qs[idx + 128] * sn
                          : qs[idx] * c + qs[idx - 128] * sn;
      qbf[((size_t)(b * S_) + s) * HHD_ + idx] = __float2bfloat16(v);
    } else if (idx < HHD_ + HD_) {
      int d = idx - HHD_, i = d & 127;
      float fr = p * expf(-LN * (float)i);
      float c = cosf(fr), sn = sinf(fr);
      float v = (d < 128) ? ks[d] * c - ks[d + 128] * sn
                          : ks[d] * c + ks[d - 128] * sn;
      kbf[((size_t)(b * S_) + s) * HD_ + d] = __float2bfloat16(v);
    } else {
      int d = idx - HHD_ - HD_;
      vT[((size_t)(b * HD_) + d) * S_ + s] = vs[d];
    }
  }
}

// ---------------------------------------------------------------------------
// Generic bf16 MFMA GEMM: C[M][N] = A[M][K] @ Bt[N][K]^T, fp32 accumulate.
// 128x128 tile, 4 waves (64x64 each), BK=64, padded LDS (stride 72).
// MODE 0: out f32 = acc
// MODE 1: out bf16 = acc
// MODE 2: out f32 = aux1[m][n] + acc                         (residual)
// MODE 3: out f32 = aux1[m][n] + aux2[m/rpb][n]*acc          (gated residual)
// MODE 4: out bf16 = gelu_tanh(auxg[m][n]) * acc             (gate*up fuse)
// ---------------------------------------------------------------------------
template <int MODE>
__global__ __launch_bounds__(256, 2) void gemm_bt(
    const bf16* __restrict__ A, const bf16* __restrict__ Bt,
    int M, int N, int K,
    float* outf, bf16* outb,
    const float* aux1, const float* aux2, int aux2_stride, int rows_per_b,
    const bf16* auxg) {
  constexpr int LDT = 72;  // 64 + 8 pad: stride 144B -> 2-way LDS conflict (free)
  __shared__ bf16 As[128 * LDT];
  __shared__ bf16 Bs[128 * LDT];
  const int tid = threadIdx.x;
  const int wid = tid >> 6, l = tid & 63;
  const int lr = l >> 4, lc = l & 15;
  const int wr = wid >> 1, wc = wid & 1;
  const int m0 = blockIdx.y * 128, n0 = blockIdx.x * 128;

  f32x4 acc[4][4];
#pragma unroll
  for (int i = 0; i < 4; i++)
#pragma unroll
    for (int j = 0; j < 4; j++) acc[i][j] = (f32x4){0.f, 0.f, 0.f, 0.f};

  for (int k0 = 0; k0 < K; k0 += 64) {
    __syncthreads();
#pragma unroll
    for (int i = 0; i < 4; i++) {
      int c = i * 256 + tid;
      int row = c >> 3, col = (c & 7) * 8;
      *reinterpret_cast<uint4*>(&As[row * LDT + col]) =
          *reinterpret_cast<const uint4*>(&A[(size_t)(m0 + row) * K + k0 + col]);
      *reinterpret_cast<uint4*>(&Bs[row * LDT + col]) =
          *reinterpret_cast<const uint4*>(&Bt[(size_t)(n0 + row) * K + k0 + col]);
    }
    __syncthreads();
#pragma unroll
    for (int kk = 0; kk < 2; kk++) {
      bf16x8 af[4], bfr[4];
#pragma unroll
      for (int mi = 0; mi < 4; mi++)
        af[mi] = *reinterpret_cast<const bf16x8*>(
            &As[(wr * 64 + mi * 16 + lc) * LDT + kk * 32 + lr * 8]);
#pragma unroll
      for (int ni = 0; ni < 4; ni++)
        bfr[ni] = *reinterpret_cast<const bf16x8*>(
            &Bs[(wc * 64 + ni * 16 + lc) * LDT + kk * 32 + lr * 8]);
#pragma unroll
      for (int mi = 0; mi < 4; mi++)
#pragma unroll
        for (int ni = 0; ni < 4; ni++)
          acc[mi][ni] = __builtin_amdgcn_mfma_f32_16x16x32_bf16(
              af[mi], bfr[ni], acc[mi][ni], 0, 0, 0);
    }
  }

#pragma unroll
  for (int mi = 0; mi < 4; mi++) {
#pragma unroll
    for (int ni = 0; ni < 4; ni++) {
#pragma unroll
      for (int r = 0; r < 4; r++) {
        int m = m0 + wr * 64 + mi * 16 + lr * 4 + r;
        int n = n0 + wc * 64 + ni * 16 + lc;
        size_t idx = (size_t)m * N + n;
        float v = acc[mi][ni][r];
        if constexpr (MODE == 0) {
          outf[idx] = v;
        } else if constexpr (MODE == 1) {
          outb[idx] = __float2bfloat16(v);
        } else if constexpr (MODE == 2) {
          outf[idx] = aux1[idx] + v;
        } else if constexpr (MODE == 3) {
          outf[idx] = aux1[idx] + aux2[(size_t)(m / rows_per_b) * aux2_stride + n] * v;
        } else {  // MODE 4
          float g = __bfloat162float(auxg[idx]);
          float t = g + 0.044715f * g * g * g;
          float gl = 0.5f * g * (1.f + tanhf(0.7978845608028654f * t));
          outb[idx] = __float2bfloat16(gl * v);
        }
      }
    }
  }
}

// ---------------------------------------------------------------------------
// Flash attention, MQA (1 KV head), online softmax.
// Block = (q-tile of 64, head, batch); 4 waves x 16 q-rows.
// ---------------------------------------------------------------------------
__global__ __launch_bounds__(256, 1) void attn_kernel(
    const bf16* __restrict__ qbf, const bf16* __restrict__ kbf,
    const bf16* __restrict__ vT,
    const int* __restrict__ cs, const int* __restrict__ pad,
    bf16* __restrict__ a0, bf16* __restrict__ a1) {
  const int qt = blockIdx.x, h = blockIdx.y, b = blockIdx.z;
  const int tid = threadIdx.x, wid = tid >> 6, l = tid & 63;
  const int lr = l >> 4, lc = l & 15;
  constexpr int LK = 264;  // 256 + 8 pad
  constexpr int LV = 72;   // 64 + 8 pad
  __shared__ bf16 Ks[64 * LK];
  __shared__ bf16 Vt[128 * LV];
  __shared__ bf16 Ps[4][16 * LV];
  __shared__ int csk[64];

  const int qrow0 = qt * 64 + wid * 16;
  bf16x8 qf[8];
#pragma unroll
  for (int ks = 0; ks < 8; ks++)
    qf[ks] = *reinterpret_cast<const bf16x8*>(
        &qbf[((size_t)(b * S_) + qrow0 + lc) * HHD_ + h * HD_ + ks * 32 + lr * 8]);

  float m_run[4], l_run[4];
  int csq[4], qpad[4];
#pragma unroll
  for (int r = 0; r < 4; r++) {
    int qr = qrow0 + lr * 4 + r;
    csq[r] = cs[b * S_ + qr];
    qpad[r] = pad[b * S_ + qr];
    m_run[r] = -3.0e38f;
    l_run[r] = 0.f;
  }
  f32x4 acc_o[16];
#pragma unroll
  for (int i = 0; i < 16; i++) acc_o[i] = (f32x4){0.f, 0.f, 0.f, 0.f};

  for (int kt = 0; kt < 13; ++kt) {
    __syncthreads();
    {  // stage K tile [64][256]
      int row = tid >> 2, cc = (tid & 3) * 64;
      const bf16* src = &kbf[((size_t)(b * S_) + kt * 64 + row) * HD_ + cc];
#pragma unroll
      for (int i = 0; i < 8; i++)
        *reinterpret_cast<uint4*>(&Ks[row * LK + cc + i * 8]) =
            *reinterpret_cast<const uint4*>(&src[i * 8]);
    }
    if (tid < 64) {
      int ki = b * S_ + kt * 64 + tid;
      csk[tid] = pad[ki] ? cs[ki] : 0x7fffffff;
    }
    {  // stage V^T half 0: d in [0,128)
      int d = tid >> 1, kc = (tid & 1) * 32;
      const bf16* src = &vT[((size_t)(b * HD_) + d) * S_ + kt * 64 + kc];
#pragma unroll
      for (int i = 0; i < 4; i++)
        *reinterpret_cast<uint4*>(&Vt[d * LV + kc + i * 8]) =
            *reinterpret_cast<const uint4*>(&src[i * 8]);
    }
    __syncthreads();

    // scores: 16 q-rows x 64 keys per wave
    f32x4 sc[4];
#pragma unroll
    for (int nt = 0; nt < 4; nt++) sc[nt] = (f32x4){0.f, 0.f, 0.f, 0.f};
#pragma unroll
    for (int ks = 0; ks < 8; ks++) {
#pragma unroll
      for (int nt = 0; nt < 4; nt++) {
        bf16x8 kf = *reinterpret_cast<const bf16x8*>(
            &Ks[(nt * 16 + lc) * LK + ks * 32 + lr * 8]);
        sc[nt] = __builtin_amdgcn_mfma_f32_16x16x32_bf16(qf[ks], kf, sc[nt], 0, 0, 0);
      }
    }
    // scale + mask + row max
    float rowmax[4] = {-3.0e38f, -3.0e38f, -3.0e38f, -3.0e38f};
#pragma unroll
    for (int nt = 0; nt < 4; nt++) {
      int ck = csk[nt * 16 + lc];
#pragma unroll
      for (int r = 0; r < 4; r++) {
        float s = sc[nt][r] * 0.0625f;  // HD^-0.5
        bool ok = (ck <= csq[r]) && (qpad[r] > 0);
        s = ok ? s : -1.0e9f;
        sc[nt][r] = s;
        rowmax[r] = fmaxf(rowmax[r], s);
      }
    }
#pragma unroll
    for (int r = 0; r < 4; r++) {
      rowmax[r] = fmaxf(rowmax[r], __shfl_xor(rowmax[r], 1));
      rowmax[r] = fmaxf(rowmax[r], __shfl_xor(rowmax[r], 2));
      rowmax[r] = fmaxf(rowmax[r], __shfl_xor(rowmax[r], 4));
      rowmax[r] = fmaxf(rowmax[r], __shfl_xor(rowmax[r], 8));
    }
    float fs[4], rowsum[4];
#pragma unroll
    for (int r = 0; r < 4; r++) {
      float mnew = fmaxf(m_run[r], rowmax[r]);
      fs[r] = __expf(m_run[r] - mnew);
      m_run[r] = mnew;
      rowsum[r] = 0.f;
    }
#pragma unroll
    for (int nt = 0; nt < 4; nt++)
#pragma unroll
      for (int r = 0; r < 4; r++) {
        float p = __expf(sc[nt][r] - m_run[r]);
        sc[nt][r] = p;
        rowsum[r] += p;
      }
#pragma unroll
    for (int r = 0; r < 4; r++) {
      rowsum[r] += __shfl_xor(rowsum[r], 1);
      rowsum[r] += __shfl_xor(rowsum[r], 2);
      rowsum[r] += __shfl_xor(rowsum[r], 4);
      rowsum[r] += __shfl_xor(rowsum[r], 8);
      l_run[r] = l_run[r] * fs[r] + rowsum[r];
    }
#pragma unroll
    for (int dt = 0; dt < 16; dt++)
#pragma unroll
      for (int r = 0; r < 4; r++) acc_o[dt][r] *= fs[r];
    // P -> LDS (per-wave region), then re-read as A-fragments
#pragma unroll
    for (int nt = 0; nt < 4; nt++)
#pragma unroll
      for (int r = 0; r < 4; r++)
        Ps[wid][(lr * 4 + r) * LV + nt * 16 + lc] = __float2bfloat16(sc[nt][r]);
    __syncthreads();
    bf16x8 pf[2];
    pf[0] = *reinterpret_cast<const bf16x8*>(&Ps[wid][lc * LV + lr * 8]);
    pf[1] = *reinterpret_cast<const bf16x8*>(&Ps[wid][lc * LV + 32 + lr * 8]);
#pragma unroll
    for (int dt = 0; dt < 8; dt++) {
#pragma unroll
      for (int kk = 0; kk < 2; kk++) {
        bf16x8 vf = *reinterpret_cast<const bf16x8*>(
            &Vt[(dt * 16 + lc) * LV + kk * 32 + lr * 8]);
        acc_o[dt] = __builtin_amdgcn_mfma_f32_16x16x32_bf16(pf[kk], vf, acc_o[dt], 0, 0, 0);
      }
    }
    __syncthreads();
    {  // stage V^T half 1: d in [128,256)
      int d = tid >> 1, kc = (tid & 1) * 32;
      const bf16* src = &vT[((size_t)(b * HD_) + 128 + d) * S_ + kt * 64 + kc];
#pragma unroll
      for (int i = 0; i < 4; i++)
        *reinterpret_cast<uint4*>(&Vt[d * LV + kc + i * 8]) =
            *reinterpret_cast<const uint4*>(&src[i * 8]);
    }
    __syncthreads();
#pragma unroll
    for (int dt = 8; dt < 16; dt++) {
#pragma unroll
      for (int kk = 0; kk < 2; kk++) {
        bf16x8 vf = *reinterpret_cast<const bf16x8*>(
            &Vt[((dt - 8) * 16 + lc) * LV + kk * 32 + lr * 8]);
        acc_o[dt] = __builtin_amdgcn_mfma_f32_16x16x32_bf16(pf[kk], vf, acc_o[dt], 0, 0, 0);
      }
    }
  }

  float inv[4];
#pragma unroll
  for (int r = 0; r < 4; r++) inv[r] = 1.f / l_run[r];
#pragma unroll
  for (int dt = 0; dt < 16; dt++) {
#pragma unroll
    for (int r = 0; r < 4; r++) {
      int qr = qrow0 + lr * 4 + r;
      int col = h * HD_ + dt * 16 + lc;
      float v = acc_o[dt][r] * inv[r];
      if (qr < S1_)
        a0[((size_t)(b * S1_) + qr) * HHD_ + col] = __float2bfloat16(v);
      else
        a1[((size_t)(b * S2_) + qr - S1_) * HHD_ + col] = __float2bfloat16(v);
    }
  }
}

// ---------------------------------------------------------------------------
extern "C" void kernel_launch(void* const* d_in, const int* in_sizes, int n_in,
                              void* d_out, int out_size, void* d_ws, size_t ws_size,
                              hipStream_t stream) {
  const float* x0       = (const float*)d_in[0];
  const float* x1       = (const float*)d_in[1];
  const float* cond1    = (const float*)d_in[2];
  const float* w_q0     = (const float*)d_in[3];
  const float* w_k0     = (const float*)d_in[4];
  const float* w_v0     = (const float*)d_in[5];
  const float* w_o0     = (const float*)d_in[6];
  const float* norm1_w0 = (const float*)d_in[7];
  const float* norm2_w0 = (const float*)d_in[8];
  const float* w_gate0  = (const float*)d_in[9];
  const float* w_up0    = (const float*)d_in[10];
  const float* w_down0  = (const float*)d_in[11];
  const float* w_q1     = (const float*)d_in[12];
  const float* w_k1     = (const float*)d_in[13];
  const float* w_v1     = (const float*)d_in[14];
  const float* w_o1     = (const float*)d_in[15];
  const float* ada_in_w1   = (const float*)d_in[16];
  const float* ada_in_b1   = (const float*)d_in[17];
  const float* ada_post_w1 = (const float*)d_in[18];
  const float* ada_post_b1 = (const float*)d_in[19];
  const float* w_gate1  = (const float*)d_in[20];
  const float* w_up1    = (const float*)d_in[21];
  const float* w_down1  = (const float*)d_in[22];
  const int* pad_masks  = (const int*)d_in[23];
  const int* att_masks  = (const int*)d_in[24];

  char* wsp = (char*)d_ws;
  size_t off = 0;
  auto alloc = [&](size_t bytes) -> void* {
    void* p = wsp + off;
    off += (bytes + 255) & ~(size_t)255;
    return p;
  };

  // bf16 transposed weights
  bf16* wTq0 = (bf16*)alloc((size_t)2048 * 2048 * 2);
  bf16* wTk0 = (bf16*)alloc((size_t)256 * 2048 * 2);
  bf16* wTv0 = (bf16*)alloc((size_t)256 * 2048 * 2);
  bf16* wTo0 = (bf16*)alloc((size_t)2048 * 2048 * 2);
  bf16* wTg0 = (bf16*)alloc((size_t)16384 * 2048 * 2);
  bf16* wTu0 = (bf16*)alloc((size_t)16384 * 2048 * 2);
  bf16* wTd0 = (bf16*)alloc((size_t)2048 * 16384 * 2);
  bf16* wTq1 = (bf16*)alloc((size_t)2048 * 1024 * 2);
  bf16* wTk1 = (bf16*)alloc((size_t)256 * 1024 * 2);
  bf16* wTv1 = (bf16*)alloc((size_t)256 * 1024 * 2);
  bf16* wTo1 = (bf16*)alloc((size_t)1024 * 2048 * 2);
  bf16* wTg1 = (bf16*)alloc((size_t)4096 * 1024 * 2);
  bf16* wTu1 = (bf16*)alloc((size_t)4096 * 1024 * 2);
  bf16* wTd1 = (bf16*)alloc((size_t)1024 * 4096 * 2);
  // activations / scratch
  float* mod_in   = (float*)alloc((size_t)B_ * 2 * D1_ * 4);
  float* mod_post = (float*)alloc((size_t)B_ * 2 * D1_ * 4);
  int* pos = (int*)alloc((size_t)B_ * S_ * 4);
  int* cs  = (int*)alloc((size_t)B_ * S_ * 4);
  bf16* h0 = (bf16*)alloc((size_t)B_ * S1_ * D0_ * 2);
  bf16* h1 = (bf16*)alloc((size_t)B_ * S2_ * D1_ * 2);
  float* q0f = (float*)alloc((size_t)B_ * S1_ * HHD_ * 4);
  float* k0f = (float*)alloc((size_t)B_ * S1_ * HD_ * 4);
  bf16* v0b  = (bf16*)alloc((size_t)B_ * S1_ * HD_ * 2);
  float* q1f = (float*)alloc((size_t)B_ * S2_ * HHD_ * 4);
  float* k1f = (float*)alloc((size_t)B_ * S2_ * HD_ * 4);
  bf16* v1b  = (bf16*)alloc((size_t)B_ * S2_ * HD_ * 2);
  bf16* qbf = (bf16*)alloc((size_t)B_ * S_ * HHD_ * 2);
  bf16* kbf = (bf16*)alloc((size_t)B_ * S_ * HD_ * 2);
  bf16* vT  = (bf16*)alloc((size_t)B_ * HD_ * S_ * 2);
  bf16* a0 = (bf16*)alloc((size_t)B_ * S1_ * HHD_ * 2);
  bf16* a1 = (bf16*)alloc((size_t)B_ * S2_ * HHD_ * 2);
  bf16* G0 = (bf16*)alloc((size_t)B_ * S1_ * F0_ * 2);
  bf16* G1 = (bf16*)alloc((size_t)B_ * S2_ * F1_ * 2);
  // region reuse (lifetimes disjoint): r0 <- q0f, r1 <- k0f, y0 <- h0, y1 <- h1
  float* r0 = q0f;
  float* r1 = k0f;
  bf16* y0 = h0;
  bf16* y1 = h1;

  float* out0 = (float*)d_out;
  float* out1 = (float*)d_out + (size_t)B_ * S1_ * D0_;

  // 1) weight transposes (fp32 [K][N] -> bf16 [N][K])
  auto T = [&](const float* w, bf16* dst, int K, int N) {
    transpose_bf16_kernel<<<dim3(N / 32, K / 32), 256, 0, stream>>>(w, dst, K, N);
  };
  T(w_q0, wTq0, 2048, 2048);
  T(w_k0, wTk0, 2048, 256);
  T(w_v0, wTv0, 2048, 256);
  T(w_o0, wTo0, 2048, 2048);
  T(w_gate0, wTg0, 2048, 16384);
  T(w_up0,   wTu0, 2048, 16384);
  T(w_down0, wTd0, 16384, 2048);
  T(w_q1, wTq1, 1024, 2048);
  T(w_k1, wTk1, 1024, 256);
  T(w_v1, wTv1, 1024, 256);
  T(w_o1, wTo1, 2048, 1024);
  T(w_gate1, wTg1, 1024, 4096);
  T(w_up1,   wTu1, 1024, 4096);
  T(w_down1, wTd1, 4096, 1024);

  // 2) scans + AdaLN modulation
  scan_kernel<<<1, 64, 0, stream>>>(pad_masks, att_masks, pos, cs);
  ada_kernel<<<dim3(2 * D1_ / 256, B_), 256, 0, stream>>>(cond1, ada_in_w1, ada_in_b1, mod_in);
  ada_kernel<<<dim3(2 * D1_ / 256, B_), 256, 0, stream>>>(cond1, ada_post_w1, ada_post_b1, mod_post);

  // 3) input norms
  rms_kernel<false><<<B_ * S1_, 256, 0, stream>>>(x0, D0_, norm1_w0, 0, 1, h0);
  rms_kernel<true><<<B_ * S2_, 256, 0, stream>>>(x1, D1_, mod_in, 2 * D1_, S2_, h1);

  // 4) QKV projections
  gemm_bt<0><<<dim3(HHD_ / 128, (B_ * S1_) / 128), 256, 0, stream>>>(
      h0, wTq0, B_ * S1_, HHD_, D0_, q0f, nullptr, nullptr, nullptr, 0, 1, nullptr);
  gemm_bt<0><<<dim3(HD_ / 128, (B_ * S1_) / 128), 256, 0, stream>>>(
      h0, wTk0, B_ * S1_, HD_, D0_, k0f, nullptr, nullptr, nullptr, 0, 1, nullptr);
  gemm_bt<1><<<dim3(HD_ / 128, (B_ * S1_) / 128), 256, 0, stream>>>(
      h0, wTv0, B_ * S1_, HD_, D0_, nullptr, v0b, nullptr, nullptr, 0, 1, nullptr);
  gemm_bt<0><<<dim3(HHD_ / 128, (B_ * S2_) / 128), 256, 0, stream>>>(
      h1, wTq1, B_ * S2_, HHD_, D1_, q1f, nullptr, nullptr, nullptr, 0, 1, nullptr);
  gemm_bt<0><<<dim3(HD_ / 128, (B_ * S2_) / 128), 256, 0, stream>>>(
      h1, wTk1, B_ * S2_, HD_, D1_, k1f, nullptr, nullptr, nullptr, 0, 1, nullptr);
  gemm_bt<1><<<dim3(HD_ / 128, (B_ * S2_) / 128), 256, 0, stream>>>(
      h1, wTv1, B_ * S2_, HD_, D1_, nullptr, v1b, nullptr, nullptr, 0, 1, nullptr);

  // 5) RoPE + pack (joint sequence, V transposed)
  rope_pack_kernel<<<B_ * S_, 256, 0, stream>>>(q0f, q1f, k0f, k1f, v0b, v1b, pos,
                                                qbf, kbf, vT);

  // 6) attention
  attn_kernel<<<dim3(S_ / 64, H_, B_), 256, 0, stream>>>(qbf, kbf, vT, cs, pad_masks, a0, a1);

  // 7) output projections + residuals
  gemm_bt<2><<<dim3(D0_ / 128, (B_ * S1_) / 128), 256, 0, stream>>>(
      a0, wTo0, B_ * S1_, D0_, HHD_, r0, nullptr, x0, nullptr, 0, 1, nullptr);
  gemm_bt<3><<<dim3(D1_ / 128, (B_ * S2_) / 128), 256, 0, stream>>>(
      a1, wTo1, B_ * S2_, D1_, HHD_, r1, nullptr, x1, mod_in + D1_, 2 * D1_, S2_, nullptr);

  // 8) post norms
  rms_kernel<false><<<B_ * S1_, 256, 0, stream>>>(r0, D0_, norm2_w0, 0, 1, y0);
  rms_kernel<true><<<B_ * S2_, 256, 0, stream>>>(r1, D1_, mod_post, 2 * D1_, S2_, y1);

  // 9) MLP stream 0: gate -> (up * gelu(gate)) -> down(+residual)
  gemm_bt<1><<<dim3(F0_ / 128, (B_ * S1_) / 128), 256, 0, stream>>>(
      y0, wTg0, B_ * S1_, F0_, D0_, nullptr, G0, nullptr, nullptr, 0, 1, nullptr);
  gemm_bt<4><<<dim3(F0_ / 128, (B_ * S1_) / 128), 256, 0, stream>>>(
      y0, wTu0, B_ * S1_, F0_, D0_, nullptr, G0, nullptr, nullptr, 0, 1, G0);
  gemm_bt<2><<<dim3(D0_ / 128, (B_ * S1_) / 128), 256, 0, stream>>>(
      G0, wTd0, B_ * S1_, D0_, F0_, out0, nullptr, r0, nullptr, 0, 1, nullptr);

  // 10) MLP stream 1 (gated residual)
  gemm_bt<1><<<dim3(F1_ / 128, (B_ * S2_) / 128), 256, 0, stream>>>(
      y1, wTg1, B_ * S2_, F1_, D1_, nullptr, G1, nullptr, nullptr, 0, 1, nullptr);
  gemm_bt<4><<<dim3(F1_ / 128, (B_ * S2_) / 128), 256, 0, stream>>>(
      y1, wTu1, B_ * S2_, F1_, D1_, nullptr, G1, nullptr, nullptr, 0, 1, G1);
  gemm_bt<3><<<dim3(D1_ / 128, (B_ * S2_) / 128), 256, 0, stream>>>(
      G1, wTd1, B_ * S2_, D1_, F1_, out1, nullptr, r1, mod_post + D1_, 2 * D1_, S2_, nullptr);

  (void)in_sizes; (void)n_in; (void)out_size; (void)ws_size;
}